// Round 6
// baseline (703.211 us; speedup 1.0000x reference)
//
#include <hip/hip_runtime.h>
#include <hip/hip_bf16.h>
#include <cstdint>

// U: 1024x1024, V: 2048x2048, out = Qu @ Qv[:1024,:]  (f32 1024x2048)
#define CI 1024
#define CO 2048
#define NB 256   // WY block size
#define BK 16    // GEMM K-tile
#define TM 32    // chain-GEMM tile rows
#define TN 64    // chain-GEMM tile cols

// ---------------- utility ----------------

__global__ __launch_bounds__(256) void colnorm2(const float* __restrict__ M, float* __restrict__ n2, int d) {
    int c = blockIdx.x * 256 + threadIdx.x;
    int r0 = blockIdx.y * 64;
    float s = 0.0f;
    for (int r = r0; r < r0 + 64; ++r) {
        float v = M[(size_t)r * d + c];
        s = fmaf(v, v, s);
    }
    atomicAdd(&n2[c], s);
}

// W = [I | 0]   (1024 x 2048)
__global__ __launch_bounds__(256) void init_W(float* __restrict__ W) {
    int c = blockIdx.x * 256 + threadIdx.x;
    int r = blockIdx.y;
    W[(size_t)r * CO + c] = (c == r) ? 1.0f : 0.0f;
}

// ---------------- Gram partials: Spart[z] = A[:,zb]^T A[:,zb] over K-chunk ks ----------------
__global__ __launch_bounds__(128) void gram_part(const float* __restrict__ A, int d, int split,
                                                 float* __restrict__ Spart) {
    int z = blockIdx.z;
    int zb = z / split, ks = z % split;
    int chunk = d / split;
    int c0 = zb * NB;
    float* S = Spart + (size_t)z * NB * NB;
    __shared__ float As[BK][64];
    __shared__ float Bs[BK][64];
    int tid = threadIdx.x;
    int i0 = blockIdx.y * 64, j0 = blockIdx.x * 64;
    int tm = (tid >> 4) * 8, tn = (tid & 15) * 4;
    int sk = tid >> 4;
    int sc = (tid & 15) * 4;
    float acc[8][4] = {};
    int kb = ks * chunk, ke = kb + chunk;
    for (int k0 = kb; k0 < ke; k0 += BK) {
        #pragma unroll
        for (int p = 0; p < 2; ++p) {
            int kk = sk + p * 8;
            *(float4*)&As[kk][sc] = *(const float4*)(A + (size_t)(k0 + kk) * d + c0 + i0 + sc);
            *(float4*)&Bs[kk][sc] = *(const float4*)(A + (size_t)(k0 + kk) * d + c0 + j0 + sc);
        }
        __syncthreads();
        #pragma unroll
        for (int k = 0; k < BK; ++k) {
            float4 alo = *(const float4*)&As[k][tm];
            float4 ahi = *(const float4*)&As[k][tm + 4];
            float4 bv  = *(const float4*)&Bs[k][tn];
            float a[8] = {alo.x, alo.y, alo.z, alo.w, ahi.x, ahi.y, ahi.z, ahi.w};
            float b[4] = {bv.x, bv.y, bv.z, bv.w};
            #pragma unroll
            for (int i = 0; i < 8; ++i)
                #pragma unroll
                for (int j = 0; j < 4; ++j) acc[i][j] = fmaf(a[i], b[j], acc[i][j]);
        }
        __syncthreads();
    }
    #pragma unroll
    for (int i = 0; i < 8; ++i) {
        float4 v = make_float4(acc[i][0], acc[i][1], acc[i][2], acc[i][3]);
        *(float4*)(S + (size_t)(i0 + tm + i) * NB + j0 + tn) = v;
    }
}

// S[b] = sum_s Spart[b*split + s]
__global__ __launch_bounds__(256) void reduce_S(const float* __restrict__ src, float* __restrict__ dst, int split) {
    int b = blockIdx.y;
    int i = blockIdx.x * 256 + threadIdx.x;
    const float* p = src + (size_t)b * split * NB * NB + i;
    float acc = 0.0f;
    for (int s = 0; s < split; ++s) acc += p[(size_t)s * NB * NB];
    dst[(size_t)b * NB * NB + i] = acc;
}

// ---------------- Mt = (D T D)^T, T = (0.5 I + triu(D S D, 1))^{-1} ----------------
// One wave per (column j, matrix b). Depth-8 register prefetch of S rows (row k-8 issued while
// row k is consumed) hides L2 latency; chain is padded to a multiple of 8 steps (fake steps are
// no-ops: x[k>j]==0 and their slots hold 0). Output written TRANSPOSED (Mt[j][i]) so the wave's
// store is 4 contiguous 256B segments (fixes 16x write amplification of the column-strided store).
__global__ __launch_bounds__(64) void trinv_scaled(const float* __restrict__ Sall, float* __restrict__ Mtall,
                                                   const float* __restrict__ n2u, const float* __restrict__ n2v) {
    int j = blockIdx.x;
    int b = blockIdx.y;
    const float* S = Sall + (size_t)b * NB * NB;
    float* Mt = Mtall + (size_t)b * NB * NB;
    const float* n2 = (b < 4) ? (n2u + b * NB) : (n2v + (size_t)(b - 4) * NB);
    int l = threadIdx.x;
    float in0 = 1.0f / sqrtf(n2[l]);
    float in1 = 1.0f / sqrtf(n2[l + 64]);
    float in2 = 1.0f / sqrtf(n2[l + 128]);
    float in3 = 1.0f / sqrtf(n2[l + 192]);
    float invnj = 1.0f / sqrtf(n2[j]);
    float i20 = in0 * in0, i21 = in1 * in1, i22 = in2 * in2, i23 = in3 * in3;
    float x0 = 0, x1 = 0, x2 = 0, x3 = 0;
    float a0 = 0, a1 = 0, a2 = 0, a3 = 0;
    int jq = j >> 6, jr = j & 63;
    if (l == jr) {
        float yj = 2.0f * invnj;
        if (jq == 0) x0 = yj; else if (jq == 1) x1 = yj; else if (jq == 2) x2 = yj; else x3 = yj;
    }
    int jpad = (j + 7) & ~7;

    float q00=0,q01=0,q02=0,q03=0, q10=0,q11=0,q12=0,q13=0;
    float q20=0,q21=0,q22=0,q23=0, q30=0,q31=0,q32=0,q33=0;
    float q40=0,q41=0,q42=0,q43=0, q50=0,q51=0,q52=0,q53=0;
    float q60=0,q61=0,q62=0,q63=0, q70=0,q71=0,q72=0,q73=0;

#define LOADROW(Q0,Q1,Q2,Q3, ROW) \
    { int _r = (ROW); if (_r >= 1 && _r <= j) { const float* Sp = S + (size_t)_r * NB; \
        Q0 = Sp[l]; Q1 = Sp[l+64]; Q2 = Sp[l+128]; Q3 = Sp[l+192]; } }

    LOADROW(q00,q01,q02,q03, jpad - 0)
    LOADROW(q10,q11,q12,q13, jpad - 1)
    LOADROW(q20,q21,q22,q23, jpad - 2)
    LOADROW(q30,q31,q32,q33, jpad - 3)
    LOADROW(q40,q41,q42,q43, jpad - 4)
    LOADROW(q50,q51,q52,q53, jpad - 5)
    LOADROW(q60,q61,q62,q63, jpad - 6)
    LOADROW(q70,q71,q72,q73, jpad - 7)

#define STEP(Q0,Q1,Q2,Q3) { \
    int kq = k >> 6, kr = k & 63; \
    float yk; \
    if      (kq == 0) yk = __shfl(x0, kr); \
    else if (kq == 1) yk = __shfl(x1, kr); \
    else if (kq == 2) yk = __shfl(x2, kr); \
    else              yk = __shfl(x3, kr); \
    a0 = fmaf(Q0, yk, a0); a1 = fmaf(Q1, yk, a1); \
    a2 = fmaf(Q2, yk, a2); a3 = fmaf(Q3, yk, a3); \
    int i = k - 1; int iq = i >> 6, ir = i & 63; \
    if (k <= j && l == ir) { \
        if      (iq == 0) x0 = -2.0f * i20 * a0; \
        else if (iq == 1) x1 = -2.0f * i21 * a1; \
        else if (iq == 2) x2 = -2.0f * i22 * a2; \
        else              x3 = -2.0f * i23 * a3; \
    } \
    int pr = k - 8; \
    if (pr >= 1) { const float* Sp = S + (size_t)pr * NB; \
        Q0 = Sp[l]; Q1 = Sp[l+64]; Q2 = Sp[l+128]; Q3 = Sp[l+192]; } \
    --k; }

    int k = jpad;
    int ngroups = jpad >> 3;
    for (int g = 0; g < ngroups; ++g) {
        STEP(q00,q01,q02,q03)
        STEP(q10,q11,q12,q13)
        STEP(q20,q21,q22,q23)
        STEP(q30,q31,q32,q33)
        STEP(q40,q41,q42,q43)
        STEP(q50,q51,q52,q53)
        STEP(q60,q61,q62,q63)
        STEP(q70,q71,q72,q73)
    }
#undef STEP
#undef LOADROW

    float* Mr = Mt + (size_t)j * NB;
    Mr[l      ] = x0 * invnj;
    Mr[l +  64] = x1 * invnj;
    Mr[l + 128] = x2 * invnj;
    Mr[l + 192] = x3 * invnj;
}

// ---------------- TB_z = M_z @ B_z^T with M stored TRANSPOSED (Mt[k][m] = M[m][k]) ----------------
__global__ __launch_bounds__(128) void gemm128_nt_batch(const float* __restrict__ Mtall,
                                                        const float* __restrict__ Bsrc, int d,
                                                        float* __restrict__ Call) {
    int z = blockIdx.z;
    const float* Mt = Mtall + (size_t)z * NB * NB;
    const float* B = Bsrc + (size_t)z * NB;
    float* C = Call + (size_t)z * NB * d;
    int m0 = blockIdx.y * 64, n0 = blockIdx.x * 64;
    __shared__ float As[BK][64];
    __shared__ float Bs[BK][64];
    int tid = threadIdx.x;
    int tm = (tid >> 4) * 8, tn = (tid & 15) * 4;
    int sk = tid >> 4;            // 0..7 k-row for A stage (Mt rows, contiguous in m)
    int sc = (tid & 15) * 4;
    int ar = tid >> 2;
    int ac = (tid & 3) * 4;
    float acc[8][4] = {};
    for (int k0 = 0; k0 < NB; k0 += BK) {
        #pragma unroll
        for (int p = 0; p < 2; ++p) {
            int kk = sk + p * 8;
            *(float4*)&As[kk][sc] = *(const float4*)(Mt + (size_t)(k0 + kk) * NB + m0 + sc);
        }
        #pragma unroll
        for (int p = 0; p < 2; ++p) {
            int r = ar + p * 32;
            float4 bv = *(const float4*)(B + (size_t)(n0 + r) * d + k0 + ac);
            Bs[ac + 0][r] = bv.x; Bs[ac + 1][r] = bv.y; Bs[ac + 2][r] = bv.z; Bs[ac + 3][r] = bv.w;
        }
        __syncthreads();
        #pragma unroll
        for (int k = 0; k < BK; ++k) {
            float4 alo = *(const float4*)&As[k][tm];
            float4 ahi = *(const float4*)&As[k][tm + 4];
            float4 bv  = *(const float4*)&Bs[k][tn];
            float a[8] = {alo.x, alo.y, alo.z, alo.w, ahi.x, ahi.y, ahi.z, ahi.w};
            float b[4] = {bv.x, bv.y, bv.z, bv.w};
            #pragma unroll
            for (int i = 0; i < 8; ++i)
                #pragma unroll
                for (int j = 0; j < 4; ++j) acc[i][j] = fmaf(a[i], b[j], acc[i][j]);
        }
        __syncthreads();
    }
    #pragma unroll
    for (int i = 0; i < 8; ++i) {
        float4 v = make_float4(acc[i][0], acc[i][1], acc[i][2], acc[i][3]);
        *(float4*)(C + (size_t)(m0 + tm + i) * d + n0 + tn) = v;
    }
}

// ---------------- chain GEMM 1: P0parts[z] = W @ Bblk over K-chunk z  (TMxTN, dbuf) ----------------
__global__ __launch_bounds__(128) void chain_part(const float* __restrict__ A, int ldA,
                                                  const float* __restrict__ B, int ldB,
                                                  float* __restrict__ Cparts, int kchunk) {
    int z = blockIdx.z;
    float* C = Cparts + (size_t)z * CI * NB;
    int m0 = blockIdx.y * TM, n0 = blockIdx.x * TN;
    int kb = z * kchunk;
    __shared__ float As[2][BK][TM];
    __shared__ float Bs[2][BK][TN];
    int tid = threadIdx.x;
    int tm = (tid >> 4) * 4, tn = (tid & 15) * 4;
    int ar = tid >> 2, ac = (tid & 3) * 4;
    int bk = tid >> 4, bn = (tid & 15) * 4;
    float acc[4][4] = {};
    const float* Ap = A + (size_t)(m0 + ar) * ldA + ac;
    float4 av  = *(const float4*)(Ap + kb);
    float4 bv0 = *(const float4*)(B + (size_t)(kb + bk) * ldB + n0 + bn);
    float4 bv1 = *(const float4*)(B + (size_t)(kb + bk + 8) * ldB + n0 + bn);
    As[0][ac + 0][ar] = av.x; As[0][ac + 1][ar] = av.y; As[0][ac + 2][ar] = av.z; As[0][ac + 3][ar] = av.w;
    *(float4*)&Bs[0][bk][bn] = bv0;
    *(float4*)&Bs[0][bk + 8][bn] = bv1;
    __syncthreads();
    int nt = kchunk / BK;
    for (int t = 0; t < nt; ++t) {
        int cur = t & 1;
        if (t + 1 < nt) {
            int k0 = kb + (t + 1) * BK;
            av  = *(const float4*)(Ap + k0);
            bv0 = *(const float4*)(B + (size_t)(k0 + bk) * ldB + n0 + bn);
            bv1 = *(const float4*)(B + (size_t)(k0 + bk + 8) * ldB + n0 + bn);
        }
        #pragma unroll
        for (int k = 0; k < BK; ++k) {
            float4 a = *(const float4*)&As[cur][k][tm];
            float4 b = *(const float4*)&Bs[cur][k][tn];
            float aa[4] = {a.x, a.y, a.z, a.w};
            float bb[4] = {b.x, b.y, b.z, b.w};
            #pragma unroll
            for (int i = 0; i < 4; ++i)
                #pragma unroll
                for (int j = 0; j < 4; ++j) acc[i][j] = fmaf(aa[i], bb[j], acc[i][j]);
        }
        if (t + 1 < nt) {
            int nxt = cur ^ 1;
            As[nxt][ac + 0][ar] = av.x; As[nxt][ac + 1][ar] = av.y;
            As[nxt][ac + 2][ar] = av.z; As[nxt][ac + 3][ar] = av.w;
            *(float4*)&Bs[nxt][bk][bn] = bv0;
            *(float4*)&Bs[nxt][bk + 8][bn] = bv1;
            __syncthreads();
        }
    }
    #pragma unroll
    for (int i = 0; i < 4; ++i) {
        float4 v = make_float4(acc[i][0], acc[i][1], acc[i][2], acc[i][3]);
        *(float4*)(C + (size_t)(m0 + tm + i) * NB + n0 + tn) = v;
    }
}

// ---------------- chain GEMM 2: W -= (sum_s Apart[s]) @ B  (TMxTN, dbuf, K=NB) ----------------
template<int NPART>
__global__ __launch_bounds__(128) void chain_sub_fused(const float* __restrict__ A, int ldA, size_t partStride,
                                                       const float* __restrict__ B, int ldB,
                                                       float* __restrict__ C) {
    int m0 = blockIdx.y * TM, n0 = blockIdx.x * TN;
    __shared__ float As[2][BK][TM];
    __shared__ float Bs[2][BK][TN];
    int tid = threadIdx.x;
    int tm = (tid >> 4) * 4, tn = (tid & 15) * 4;
    int ar = tid >> 2, ac = (tid & 3) * 4;
    int bk = tid >> 4, bn = (tid & 15) * 4;
    float acc[4][4] = {};
    const float* Ap = A + (size_t)(m0 + ar) * ldA + ac;
    float4 av, bv0, bv1;
    {
        av = *(const float4*)(Ap);
        #pragma unroll
        for (int s = 1; s < NPART; ++s) {
            float4 v = *(const float4*)(Ap + (size_t)s * partStride);
            av.x += v.x; av.y += v.y; av.z += v.z; av.w += v.w;
        }
        bv0 = *(const float4*)(B + (size_t)(bk) * ldB + n0 + bn);
        bv1 = *(const float4*)(B + (size_t)(bk + 8) * ldB + n0 + bn);
    }
    As[0][ac + 0][ar] = av.x; As[0][ac + 1][ar] = av.y; As[0][ac + 2][ar] = av.z; As[0][ac + 3][ar] = av.w;
    *(float4*)&Bs[0][bk][bn] = bv0;
    *(float4*)&Bs[0][bk + 8][bn] = bv1;
    __syncthreads();
    const int nt = NB / BK;
    for (int t = 0; t < nt; ++t) {
        int cur = t & 1;
        if (t + 1 < nt) {
            int k0 = (t + 1) * BK;
            av = *(const float4*)(Ap + k0);
            #pragma unroll
            for (int s = 1; s < NPART; ++s) {
                float4 v = *(const float4*)(Ap + k0 + (size_t)s * partStride);
                av.x += v.x; av.y += v.y; av.z += v.z; av.w += v.w;
            }
            bv0 = *(const float4*)(B + (size_t)(k0 + bk) * ldB + n0 + bn);
            bv1 = *(const float4*)(B + (size_t)(k0 + bk + 8) * ldB + n0 + bn);
        }
        #pragma unroll
        for (int k = 0; k < BK; ++k) {
            float4 a = *(const float4*)&As[cur][k][tm];
            float4 b = *(const float4*)&Bs[cur][k][tn];
            float aa[4] = {a.x, a.y, a.z, a.w};
            float bb[4] = {b.x, b.y, b.z, b.w};
            #pragma unroll
            for (int i = 0; i < 4; ++i)
                #pragma unroll
                for (int j = 0; j < 4; ++j) acc[i][j] = fmaf(aa[i], bb[j], acc[i][j]);
        }
        if (t + 1 < nt) {
            int nxt = cur ^ 1;
            As[nxt][ac + 0][ar] = av.x; As[nxt][ac + 1][ar] = av.y;
            As[nxt][ac + 2][ar] = av.z; As[nxt][ac + 3][ar] = av.w;
            *(float4*)&Bs[nxt][bk][bn] = bv0;
            *(float4*)&Bs[nxt][bk + 8][bn] = bv1;
            __syncthreads();
        }
    }
    #pragma unroll
    for (int i = 0; i < 4; ++i) {
        float* cp = C + (size_t)(m0 + tm + i) * CO + n0 + tn;
        float4 old = *(float4*)cp;
        old.x -= acc[i][0]; old.y -= acc[i][1]; old.z -= acc[i][2]; old.w -= acc[i][3];
        *(float4*)cp = old;
    }
}

extern "C" void kernel_launch(void* const* d_in, const int* in_sizes, int n_in,
                              void* d_out, int out_size, void* d_ws, size_t ws_size,
                              hipStream_t stream) {
    const float* U = (const float*)d_in[0];   // 1024x1024
    const float* V = (const float*)d_in[1];   // 2048x2048
    float* W = (float*)d_out;                 // 1024x2048, evolving product

    char* ws = (char*)d_ws;
    float* P0p  = (float*)(ws);                          //  8 MB: 8 x (1024x256) split-K partials
    float* S    = (float*)(ws + ((size_t)8  << 20));     //  3 MB: 12 x 256^2 (4 U then 8 V)
    float* Mt   = (float*)(ws + ((size_t)11 << 20));     //  3 MB (transposed scaled T)
    float* TBu  = (float*)(ws + ((size_t)14 << 20));     //  4 MB (4 x 256x1024)
    float* TBv  = (float*)(ws + ((size_t)18 << 20));     // 16 MB (8 x 256x2048)
    float* n2u  = (float*)(ws + ((size_t)34 << 20));     //  4 KB
    float* n2v  = n2u + CI;
    // Gram partials alias the TB region (consumed by reduce_S before TB is written)
    float* SpU  = TBu;                                   //  4 MB: 4 blk x 4 splits
    float* SpV  = TBv;                                   // 16 MB: 8 blk x 8 splits

    float* Su = S;   float* Sv = S + (size_t)4 * NB * NB;
    float* Mtu = Mt; float* Mtv = Mt + (size_t)4 * NB * NB;

    // 1) raw column norms
    hipMemsetAsync(n2u, 0, (CI + CO) * sizeof(float), stream);
    colnorm2<<<dim3(CI / 256, CI / 64), dim3(256), 0, stream>>>(U, n2u, CI);
    colnorm2<<<dim3(CO / 256, CO / 64), dim3(256), 0, stream>>>(V, n2v, CO);

    // 2) Gram partials (no atomics) + reduce + scaled triangular inverse (transposed out)
    gram_part<<<dim3(NB / 64, NB / 64, (CI / NB) * 4), dim3(128), 0, stream>>>(U, CI, 4, SpU);
    gram_part<<<dim3(NB / 64, NB / 64, (CO / NB) * 8), dim3(128), 0, stream>>>(V, CO, 8, SpV);
    reduce_S<<<dim3(NB * NB / 256, CI / NB), dim3(256), 0, stream>>>(SpU, Su, 4);
    reduce_S<<<dim3(NB * NB / 256, CO / NB), dim3(256), 0, stream>>>(SpV, Sv, 8);
    trinv_scaled<<<dim3(NB, 12), dim3(64), 0, stream>>>(S, Mt, n2u, n2v);

    // 3) TB_i = M_i @ B_i^T  (overwrites the Spart alias — already consumed)
    gemm128_nt_batch<<<dim3(CI / 64, NB / 64, CI / NB), dim3(128), 0, stream>>>(Mtu, U, CI, TBu);
    gemm128_nt_batch<<<dim3(CO / 64, NB / 64, CO / NB), dim3(128), 0, stream>>>(Mtv, V, CO, TBv);

    // 4) W = [I | 0]
    init_W<<<dim3(CO / 256, CI), dim3(256), 0, stream>>>(W);

    // 5) U-phase: W[:, :1024] -= (W[:, :1024] B_i) TB_i
    //    ib = 0 shortcut: W = [I|0]  =>  W B_0 = U[:, 0:256]  (single fused dispatch)
    chain_sub_fused<1><<<dim3(CI / TN, CI / TM), dim3(128), 0, stream>>>(U, CI, 0, TBu, CI, W);
    for (int ib = 1; ib < CI / NB; ++ib) {
        chain_part<<<dim3(NB / TN, CI / TM, 4), dim3(128), 0, stream>>>(W, CO, U + ib * NB, CI, P0p, CI / 4);
        chain_sub_fused<4><<<dim3(CI / TN, CI / TM), dim3(128), 0, stream>>>(
            P0p, NB, (size_t)CI * NB, TBu + (size_t)ib * NB * CI, CI, W);
    }
    // 6) V-phase: W -= (W B_i) TB_i, full 2048 columns
    for (int ib = 0; ib < CO / NB; ++ib) {
        chain_part<<<dim3(NB / TN, CI / TM, 8), dim3(128), 0, stream>>>(W, CO, V + ib * NB, CO, P0p, CO / 8);
        chain_sub_fused<8><<<dim3(CO / TN, CI / TM), dim3(128), 0, stream>>>(
            P0p, NB, (size_t)CI * NB, TBv + (size_t)ib * NB * CO, CO, W);
    }
}

// Round 7
// 467.400 us; speedup vs baseline: 1.5045x; 1.5045x over previous
//
#include <hip/hip_runtime.h>
#include <hip/hip_bf16.h>
#include <cstdint>

// U: 1024x1024, V: 2048x2048, out = Qu @ Qv[:1024,:]  (f32 1024x2048)
#define CI 1024
#define CO 2048
#define NB 256   // WY block size

typedef float  fx4  __attribute__((ext_vector_type(4)));
typedef short  s16x4 __attribute__((ext_vector_type(4)));
typedef short  s16x8 __attribute__((ext_vector_type(8)));
typedef unsigned short u16;

#define MFMA(a,b,c) __builtin_amdgcn_mfma_f32_16x16x32_bf16((a),(b),(c),0,0,0)

__device__ __forceinline__ u16 f2b(float x) {
    __hip_bfloat16 h = __float2bfloat16(x);
    return __builtin_bit_cast(u16, h);
}
__device__ __forceinline__ float b2f(u16 u) {
    __hip_bfloat16 h = __builtin_bit_cast(__hip_bfloat16, u);
    return __bfloat162float(h);
}

// ---------------- scalar utility kernels (unchanged) ----------------

__global__ __launch_bounds__(256) void colnorm2(const float* __restrict__ M, float* __restrict__ n2, int d) {
    int c = blockIdx.x * 256 + threadIdx.x;
    int r0 = blockIdx.y * 64;
    float s = 0.0f;
    for (int r = r0; r < r0 + 64; ++r) {
        float v = M[(size_t)r * d + c];
        s = fmaf(v, v, s);
    }
    atomicAdd(&n2[c], s);
}

__global__ __launch_bounds__(256) void init_W(float* __restrict__ W) {
    int c = blockIdx.x * 256 + threadIdx.x;
    int r = blockIdx.y;
    W[(size_t)r * CO + c] = (c == r) ? 1.0f : 0.0f;
}

__global__ __launch_bounds__(256) void reduce_S(const float* __restrict__ src, float* __restrict__ dst, int split) {
    int b = blockIdx.y;
    int i = blockIdx.x * 256 + threadIdx.x;
    const float* p = src + (size_t)b * split * NB * NB + i;
    float acc = 0.0f;
    for (int s = 0; s < split; ++s) acc += p[(size_t)s * NB * NB];
    dst[(size_t)b * NB * NB + i] = acc;
}

// ---------------- transpose + split-bf16 convert: T(a,b) = X(b,a) -> hi/lo planes ----------------
__global__ __launch_bounds__(256) void trans_planes(const float* __restrict__ X, int d,
                                                    u16* __restrict__ Th, u16* __restrict__ Tl) {
    size_t zo = (size_t)blockIdx.z * d * d;
    const float* Xz = X + zo;
    u16* Thz = Th + zo;
    u16* Tlz = Tl + zo;
    __shared__ float tile[32][33];
    int t = threadIdx.x;
    int r = t >> 3, c4 = (t & 7) * 4;
    int bx = blockIdx.x, by = blockIdx.y;
    fx4 v = *(const fx4*)(Xz + (size_t)(by * 32 + r) * d + bx * 32 + c4);
    tile[r][c4 + 0] = v[0]; tile[r][c4 + 1] = v[1]; tile[r][c4 + 2] = v[2]; tile[r][c4 + 3] = v[3];
    __syncthreads();
    int a = bx * 32 + r;
    u16 h[4], l[4];
    #pragma unroll
    for (int j = 0; j < 4; ++j) {
        float f = tile[c4 + j][r];
        u16 hb = f2b(f);
        h[j] = hb;
        l[j] = f2b(f - b2f(hb));
    }
    size_t o = (size_t)a * d + by * 32 + c4;
    *(s16x4*)&Thz[o] = *(s16x4*)&h[0];
    *(s16x4*)&Tlz[o] = *(s16x4*)&l[0];
}

// ---------------- trinv (round-5 version, unchanged): Mt = (D T D)^T ----------------
__global__ __launch_bounds__(64) void trinv_scaled(const float* __restrict__ Sall, float* __restrict__ Mtall,
                                                   const float* __restrict__ n2u, const float* __restrict__ n2v) {
    int j = blockIdx.x;
    int b = blockIdx.y;
    const float* S = Sall + (size_t)b * NB * NB;
    float* Mt = Mtall + (size_t)b * NB * NB;
    const float* n2 = (b < 4) ? (n2u + b * NB) : (n2v + (size_t)(b - 4) * NB);
    int l = threadIdx.x;
    float in0 = 1.0f / sqrtf(n2[l]);
    float in1 = 1.0f / sqrtf(n2[l + 64]);
    float in2 = 1.0f / sqrtf(n2[l + 128]);
    float in3 = 1.0f / sqrtf(n2[l + 192]);
    float invnj = 1.0f / sqrtf(n2[j]);
    float i20 = in0 * in0, i21 = in1 * in1, i22 = in2 * in2, i23 = in3 * in3;
    float x0 = 0, x1 = 0, x2 = 0, x3 = 0;
    float a0 = 0, a1 = 0, a2 = 0, a3 = 0;
    int jq = j >> 6, jr = j & 63;
    if (l == jr) {
        float yj = 2.0f * invnj;
        if (jq == 0) x0 = yj; else if (jq == 1) x1 = yj; else if (jq == 2) x2 = yj; else x3 = yj;
    }
    int jpad = (j + 7) & ~7;
    float q00=0,q01=0,q02=0,q03=0, q10=0,q11=0,q12=0,q13=0;
    float q20=0,q21=0,q22=0,q23=0, q30=0,q31=0,q32=0,q33=0;
    float q40=0,q41=0,q42=0,q43=0, q50=0,q51=0,q52=0,q53=0;
    float q60=0,q61=0,q62=0,q63=0, q70=0,q71=0,q72=0,q73=0;
#define LOADROW(Q0,Q1,Q2,Q3, ROW) \
    { int _r = (ROW); if (_r >= 1 && _r <= j) { const float* Sp = S + (size_t)_r * NB; \
        Q0 = Sp[l]; Q1 = Sp[l+64]; Q2 = Sp[l+128]; Q3 = Sp[l+192]; } }
    LOADROW(q00,q01,q02,q03, jpad - 0)
    LOADROW(q10,q11,q12,q13, jpad - 1)
    LOADROW(q20,q21,q22,q23, jpad - 2)
    LOADROW(q30,q31,q32,q33, jpad - 3)
    LOADROW(q40,q41,q42,q43, jpad - 4)
    LOADROW(q50,q51,q52,q53, jpad - 5)
    LOADROW(q60,q61,q62,q63, jpad - 6)
    LOADROW(q70,q71,q72,q73, jpad - 7)
#define STEP(Q0,Q1,Q2,Q3) { \
    int kq = k >> 6, kr = k & 63; \
    float yk; \
    if      (kq == 0) yk = __shfl(x0, kr); \
    else if (kq == 1) yk = __shfl(x1, kr); \
    else if (kq == 2) yk = __shfl(x2, kr); \
    else              yk = __shfl(x3, kr); \
    a0 = fmaf(Q0, yk, a0); a1 = fmaf(Q1, yk, a1); \
    a2 = fmaf(Q2, yk, a2); a3 = fmaf(Q3, yk, a3); \
    int i = k - 1; int iq = i >> 6, ir = i & 63; \
    if (k <= j && l == ir) { \
        if      (iq == 0) x0 = -2.0f * i20 * a0; \
        else if (iq == 1) x1 = -2.0f * i21 * a1; \
        else if (iq == 2) x2 = -2.0f * i22 * a2; \
        else              x3 = -2.0f * i23 * a3; \
    } \
    int pr = k - 8; \
    if (pr >= 1) { const float* Sp = S + (size_t)pr * NB; \
        Q0 = Sp[l]; Q1 = Sp[l+64]; Q2 = Sp[l+128]; Q3 = Sp[l+192]; } \
    --k; }
    int k = jpad;
    int ngroups = jpad >> 3;
    for (int g = 0; g < ngroups; ++g) {
        STEP(q00,q01,q02,q03)
        STEP(q10,q11,q12,q13)
        STEP(q20,q21,q22,q23)
        STEP(q30,q31,q32,q33)
        STEP(q40,q41,q42,q43)
        STEP(q50,q51,q52,q53)
        STEP(q60,q61,q62,q63)
        STEP(q70,q71,q72,q73)
    }
#undef STEP
#undef LOADROW
    float* Mr = Mt + (size_t)j * NB;
    Mr[l      ] = x0 * invnj;
    Mr[l +  64] = x1 * invnj;
    Mr[l + 128] = x2 * invnj;
    Mr[l + 192] = x3 * invnj;
}

// ---------------- MFMA common pieces ----------------
// LDS tiles: [64 rows][40 cols] u16 (pad 32->40 keeps ds_read_b64 2-way max).
// Wave w of 4: quadrant (wr=w>>1, wc=w&1) -> 32x32 out, 2x2 of 16x16x32 frags.
// Split-bf16: acc += hi*hi + hi*lo + lo*hi.

__device__ __forceinline__ void mma_step(const u16 Ah[][40], const u16 Al[][40],
                                         const u16 Bh[][40], const u16 Bl[][40],
                                         int wr, int wc, int lane, fx4 acc[2][2]) {
    int kb = (lane >> 4) * 8;
    int rl = lane & 15;
    s16x8 ah[2], al[2], bh[2], bl[2];
    #pragma unroll
    for (int f = 0; f < 2; ++f) {
        int ra = wr * 32 + f * 16 + rl;
        s16x4 p = *(const s16x4*)&Ah[ra][kb];
        s16x4 q = *(const s16x4*)&Ah[ra][kb + 4];
        ah[f] = __builtin_shufflevector(p, q, 0,1,2,3,4,5,6,7);
        p = *(const s16x4*)&Al[ra][kb];
        q = *(const s16x4*)&Al[ra][kb + 4];
        al[f] = __builtin_shufflevector(p, q, 0,1,2,3,4,5,6,7);
        int rb = wc * 32 + f * 16 + rl;
        p = *(const s16x4*)&Bh[rb][kb];
        q = *(const s16x4*)&Bh[rb][kb + 4];
        bh[f] = __builtin_shufflevector(p, q, 0,1,2,3,4,5,6,7);
        p = *(const s16x4*)&Bl[rb][kb];
        q = *(const s16x4*)&Bl[rb][kb + 4];
        bl[f] = __builtin_shufflevector(p, q, 0,1,2,3,4,5,6,7);
    }
    #pragma unroll
    for (int i = 0; i < 2; ++i)
        #pragma unroll
        for (int j = 0; j < 2; ++j) {
            acc[i][j] = MFMA(ah[i], bh[j], acc[i][j]);
            acc[i][j] = MFMA(ah[i], bl[j], acc[i][j]);
            acc[i][j] = MFMA(al[i], bh[j], acc[i][j]);
        }
}

// stage 64x32 fp32 tile (optionally summing NPART partials) -> hi/lo LDS
template<int NPART>
__device__ __forceinline__ void stage_f32(const float* __restrict__ A, int ldA, size_t pstride,
                                          int m0, int k0, int t, u16 Dh[][40], u16 Dl[][40]) {
    int row = t >> 2, kc = (t & 3) * 8;
    const float* p = A + (size_t)(m0 + row) * ldA + k0 + kc;
    fx4 v0 = *(const fx4*)p;
    fx4 v1 = *(const fx4*)(p + 4);
    #pragma unroll
    for (int s = 1; s < NPART; ++s) {
        const float* q = p + (size_t)s * pstride;
        v0 += *(const fx4*)q;
        v1 += *(const fx4*)(q + 4);
    }
    u16 h[8], l[8];
    #pragma unroll
    for (int j = 0; j < 8; ++j) {
        float f = (j < 4) ? v0[j] : v1[j - 4];
        u16 hb = f2b(f);
        h[j] = hb;
        l[j] = f2b(f - b2f(hb));
    }
    *(s16x4*)&Dh[row][kc]     = *(s16x4*)&h[0];
    *(s16x4*)&Dh[row][kc + 4] = *(s16x4*)&h[4];
    *(s16x4*)&Dl[row][kc]     = *(s16x4*)&l[0];
    *(s16x4*)&Dl[row][kc + 4] = *(s16x4*)&l[4];
}

// stage 64x32 tile from precomputed bf16 hi/lo planes -> LDS
__device__ __forceinline__ void stage_planes(const u16* __restrict__ Ph, const u16* __restrict__ Pl, int ld,
                                             int n0, int k0, int t, u16 Dh[][40], u16 Dl[][40]) {
    int row = t >> 2, kc = (t & 3) * 8;
    size_t o = (size_t)(n0 + row) * ld + k0 + kc;
    s16x4 h0 = *(const s16x4*)(Ph + o);
    s16x4 h1 = *(const s16x4*)(Ph + o + 4);
    s16x4 l0 = *(const s16x4*)(Pl + o);
    s16x4 l1 = *(const s16x4*)(Pl + o + 4);
    *(s16x4*)&Dh[row][kc]     = h0;
    *(s16x4*)&Dh[row][kc + 4] = h1;
    *(s16x4*)&Dl[row][kc]     = l0;
    *(s16x4*)&Dl[row][kc + 4] = l1;
}

// ---------------- Gram partials via MFMA: Sp[z] = Xt[c0+i,:] . Xt[c0+j,:] over k-chunk ----------------
__global__ __launch_bounds__(256) void gram_mfma(const u16* __restrict__ Xh, const u16* __restrict__ Xl,
                                                 int d, int split, int chunk, float* __restrict__ Sp) {
    int z = blockIdx.z;
    int zb = z / split, ks = z % split;
    int c0 = zb * NB, kb = ks * chunk;
    float* S = Sp + (size_t)z * NB * NB;
    __shared__ u16 Ah[64][40], Al[64][40], Bh[64][40], Bl[64][40];
    int t = threadIdx.x, lane = t & 63, w = t >> 6, wr = w >> 1, wc = w & 1;
    int i0 = blockIdx.y * 64, j0 = blockIdx.x * 64;
    fx4 acc[2][2] = {};
    for (int k0 = kb; k0 < kb + chunk; k0 += 32) {
        stage_planes(Xh, Xl, d, c0 + i0, k0, t, Ah, Al);
        stage_planes(Xh, Xl, d, c0 + j0, k0, t, Bh, Bl);
        __syncthreads();
        mma_step(Ah, Al, Bh, Bl, wr, wc, lane, acc);
        __syncthreads();
    }
    #pragma unroll
    for (int fr = 0; fr < 2; ++fr)
        #pragma unroll
        for (int fc = 0; fc < 2; ++fc) {
            int row = i0 + wr * 32 + fr * 16 + ((lane >> 4) << 2);
            int col = j0 + wc * 32 + fc * 16 + (lane & 15);
            #pragma unroll
            for (int r = 0; r < 4; ++r)
                S[(size_t)(row + r) * NB + col] = acc[fr][fc][r];
        }
}

// ---------------- TBt_z = RAW_blockz @ M_z^T, emitted as bf16 hi/lo planes ----------------
// C(r,j) = sum_c RAW(r, c0+c) * M(j,c);  M given row-major via hi/lo planes (ld NB).
__global__ __launch_bounds__(256) void tbt_mfma(const float* __restrict__ RAW, int d,
                                                const u16* __restrict__ Mh, const u16* __restrict__ Ml,
                                                u16* __restrict__ TBh, u16* __restrict__ TBl) {
    int z = blockIdx.z;
    int c0 = z * NB;
    const u16* Mhz = Mh + (size_t)z * NB * NB;
    const u16* Mlz = Ml + (size_t)z * NB * NB;
    u16* Th = TBh + (size_t)z * d * NB;
    u16* Tl = TBl + (size_t)z * d * NB;
    __shared__ u16 Ah[64][40], Al[64][40], Bh[64][40], Bl[64][40];
    int t = threadIdx.x, lane = t & 63, w = t >> 6, wr = w >> 1, wc = w & 1;
    int m0 = blockIdx.y * 64, n0 = blockIdx.x * 64;
    fx4 acc[2][2] = {};
    for (int k0 = 0; k0 < NB; k0 += 32) {
        stage_f32<1>(RAW + c0, d, 0, m0, k0, t, Ah, Al);
        stage_planes(Mhz, Mlz, NB, n0, k0, t, Bh, Bl);
        __syncthreads();
        mma_step(Ah, Al, Bh, Bl, wr, wc, lane, acc);
        __syncthreads();
    }
    #pragma unroll
    for (int fr = 0; fr < 2; ++fr)
        #pragma unroll
        for (int fc = 0; fc < 2; ++fc) {
            int row = m0 + wr * 32 + fr * 16 + ((lane >> 4) << 2);
            int col = n0 + wc * 32 + fc * 16 + (lane & 15);
            #pragma unroll
            for (int r = 0; r < 4; ++r) {
                float f = acc[fr][fc][r];
                u16 hb = f2b(f);
                Th[(size_t)(row + r) * NB + col] = hb;
                Tl[(size_t)(row + r) * NB + col] = f2b(f - b2f(hb));
            }
        }
}

// ---------------- chain GEMM 1: P0parts[z] = W @ Bblk over k-chunk z (B from transposed planes) ----------------
__global__ __launch_bounds__(256) void chain_part_mfma(const float* __restrict__ W,
                                                       const u16* __restrict__ Bth, const u16* __restrict__ Btl,
                                                       int ldB, float* __restrict__ Cparts, int kchunk) {
    int z = blockIdx.z;
    float* C = Cparts + (size_t)z * CI * NB;
    int kb = z * kchunk;
    __shared__ u16 Ah[64][40], Al[64][40], Bh[64][40], Bl[64][40];
    int t = threadIdx.x, lane = t & 63, w = t >> 6, wr = w >> 1, wc = w & 1;
    int m0 = blockIdx.y * 64, n0 = blockIdx.x * 64;
    fx4 acc[2][2] = {};
    for (int k0 = kb; k0 < kb + kchunk; k0 += 32) {
        stage_f32<1>(W, CO, 0, m0, k0, t, Ah, Al);
        stage_planes(Bth, Btl, ldB, n0, k0, t, Bh, Bl);
        __syncthreads();
        mma_step(Ah, Al, Bh, Bl, wr, wc, lane, acc);
        __syncthreads();
    }
    #pragma unroll
    for (int fr = 0; fr < 2; ++fr)
        #pragma unroll
        for (int fc = 0; fc < 2; ++fc) {
            int row = m0 + wr * 32 + fr * 16 + ((lane >> 4) << 2);
            int col = n0 + wc * 32 + fc * 16 + (lane & 15);
            #pragma unroll
            for (int r = 0; r < 4; ++r)
                C[(size_t)(row + r) * NB + col] = acc[fr][fc][r];
        }
}

// ---------------- chain GEMM 2: W -= (sum_s Apart[s]) @ TB  (TB via transposed planes) ----------------
template<int NPART>
__global__ __launch_bounds__(256) void chain_sub_mfma(const float* __restrict__ A, int ldA, size_t pstride,
                                                      const u16* __restrict__ TBh, const u16* __restrict__ TBl,
                                                      float* __restrict__ W) {
    __shared__ u16 Ah[64][40], Al[64][40], Bh[64][40], Bl[64][40];
    int t = threadIdx.x, lane = t & 63, w = t >> 6, wr = w >> 1, wc = w & 1;
    int m0 = blockIdx.y * 64, n0 = blockIdx.x * 64;
    fx4 acc[2][2] = {};
    for (int k0 = 0; k0 < NB; k0 += 32) {
        stage_f32<NPART>(A, ldA, pstride, m0, k0, t, Ah, Al);
        stage_planes(TBh, TBl, NB, n0, k0, t, Bh, Bl);
        __syncthreads();
        mma_step(Ah, Al, Bh, Bl, wr, wc, lane, acc);
        __syncthreads();
    }
    #pragma unroll
    for (int fr = 0; fr < 2; ++fr)
        #pragma unroll
        for (int fc = 0; fc < 2; ++fc) {
            int row = m0 + wr * 32 + fr * 16 + ((lane >> 4) << 2);
            int col = n0 + wc * 32 + fc * 16 + (lane & 15);
            #pragma unroll
            for (int r = 0; r < 4; ++r) {
                float* p = W + (size_t)(row + r) * CO + col;
                *p -= acc[fr][fc][r];
            }
        }
}

extern "C" void kernel_launch(void* const* d_in, const int* in_sizes, int n_in,
                              void* d_out, int out_size, void* d_ws, size_t ws_size,
                              hipStream_t stream) {
    const float* U = (const float*)d_in[0];   // 1024x1024
    const float* V = (const float*)d_in[1];   // 2048x2048
    float* W = (float*)d_out;                 // 1024x2048, evolving product

    char* ws = (char*)d_ws;
    float* P0p  = (float*)(ws);                          //  8 MB: 8 x (1024x256) split-K partials
    float* S    = (float*)(ws + ((size_t)8  << 20));     //  3 MB: 12 x 256^2 (4 U then 8 V)
    float* Mt   = (float*)(ws + ((size_t)11 << 20));     //  3 MB (transposed scaled T)
    u16*   Mh   = (u16*)  (ws + ((size_t)14 << 20));     //  1.5 MB (M row-major, hi plane)
    u16*   Ml   = (u16*)  (ws + ((size_t)16 << 20));     //  1.5 MB
    u16*   TBh  = (u16*)  (ws + ((size_t)18 << 20));     // 10 MB (TBt hi: U 2 + V 8)
    u16*   TBl  = (u16*)  (ws + ((size_t)28 << 20));     // 10 MB
    u16*   Uth  = (u16*)  (ws + ((size_t)38 << 20));     //  2 MB (U^T hi)
    u16*   Utl  = (u16*)  (ws + ((size_t)40 << 20));     //  2 MB
    u16*   Vth  = (u16*)  (ws + ((size_t)42 << 20));     //  8 MB (V^T hi)
    u16*   Vtl  = (u16*)  (ws + ((size_t)50 << 20));     //  8 MB
    float* n2u  = (float*)(ws + ((size_t)58 << 20));     //  4 KB
    float* n2v  = n2u + CI;
    // Gram partials alias the TBt region (consumed by reduce_S before TBt is written)
    float* SpU  = (float*)(ws + ((size_t)18 << 20));     //  4 MB: 4 blk x 4 splits
    float* SpV  = (float*)(ws + ((size_t)22 << 20));     // 16 MB: 8 blk x 8 splits

    float* Su = S;  float* Sv = S + (size_t)4 * NB * NB;
    u16* TBhU = TBh;                       u16* TBlU = TBl;
    u16* TBhV = TBh + (size_t)4 * CI * NB; u16* TBlV = TBl + (size_t)4 * CI * NB;

    // 1) raw column norms
    hipMemsetAsync(n2u, 0, (CI + CO) * sizeof(float), stream);
    colnorm2<<<dim3(CI / 256, CI / 64), dim3(256), 0, stream>>>(U, n2u, CI);
    colnorm2<<<dim3(CO / 256, CO / 64), dim3(256), 0, stream>>>(V, n2v, CO);

    // 2) transpose+convert U,V to bf16 hi/lo planes (serves gram + chain_part B-operands)
    trans_planes<<<dim3(CI / 32, CI / 32, 1), dim3(256), 0, stream>>>(U, CI, Uth, Utl);
    trans_planes<<<dim3(CO / 32, CO / 32, 1), dim3(256), 0, stream>>>(V, CO, Vth, Vtl);

    // 3) Gram partials via MFMA + reduce + scaled triangular inverse (transposed out)
    gram_mfma<<<dim3(4, 4, 4 * 4), dim3(256), 0, stream>>>(Uth, Utl, CI, 4, CI / 4, SpU);
    gram_mfma<<<dim3(4, 4, 8 * 8), dim3(256), 0, stream>>>(Vth, Vtl, CO, 8, CO / 8, SpV);
    reduce_S<<<dim3(NB * NB / 256, 4), dim3(256), 0, stream>>>(SpU, Su, 4);
    reduce_S<<<dim3(NB * NB / 256, 8), dim3(256), 0, stream>>>(SpV, Sv, 8);
    trinv_scaled<<<dim3(NB, 12), dim3(64), 0, stream>>>(S, Mt, n2u, n2v);

    // 4) M planes: transpose Mt -> M row-major, hi/lo bf16 (12 matrices batched)
    trans_planes<<<dim3(NB / 32, NB / 32, 12), dim3(256), 0, stream>>>(Mt, NB, Mh, Ml);

    // 5) TBt_i = B_i @ M_i^T as bf16 planes (overwrites gram-partial alias -- already consumed)
    tbt_mfma<<<dim3(4, CI / 64, 4), dim3(256), 0, stream>>>(U, CI, Mh, Ml, TBhU, TBlU);
    tbt_mfma<<<dim3(4, CO / 64, 8), dim3(256), 0, stream>>>(V, CO, Mh + (size_t)4 * NB * NB,
                                                            Ml + (size_t)4 * NB * NB, TBhV, TBlV);

    // 6) W = [I | 0]
    init_W<<<dim3(CO / 256, CI), dim3(256), 0, stream>>>(W);

    // 7) U-phase: W[:, :1024] -= (W[:, :1024] B_i) TB_i
    //    ib = 0 shortcut: W = [I|0] => W B_0 = U[:, 0:256]
    chain_sub_mfma<1><<<dim3(CI / 64, CI / 64), dim3(256), 0, stream>>>(
        U, CI, 0, TBhU, TBlU, W);
    for (int ib = 1; ib < CI / NB; ++ib) {
        chain_part_mfma<<<dim3(4, CI / 64, 4), dim3(256), 0, stream>>>(
            W, Uth + (size_t)ib * NB * CI, Utl + (size_t)ib * NB * CI, CI, P0p, CI / 4);
        chain_sub_mfma<4><<<dim3(CI / 64, CI / 64), dim3(256), 0, stream>>>(
            P0p, NB, (size_t)CI * NB, TBhU + (size_t)ib * CI * NB, TBlU + (size_t)ib * CI * NB, W);
    }
    // 8) V-phase: W -= (W B_i) TB_i, full 2048 columns
    for (int ib = 0; ib < CO / NB; ++ib) {
        chain_part_mfma<<<dim3(4, CI / 64, 8), dim3(256), 0, stream>>>(
            W, Vth + (size_t)ib * NB * CO, Vtl + (size_t)ib * NB * CO, CO, P0p, CO / 8);
        chain_sub_mfma<8><<<dim3(CO / 64, CI / 64), dim3(256), 0, stream>>>(
            P0p, NB, (size_t)CI * NB, TBhV + (size_t)ib * CO * NB, TBlV + (size_t)ib * CO * NB, W);
    }
}

// Round 8
// 414.446 us; speedup vs baseline: 1.6967x; 1.1278x over previous
//
#include <hip/hip_runtime.h>
#include <hip/hip_bf16.h>
#include <cstdint>

// U: 1024x1024, V: 2048x2048, out = Qu @ Qv[:1024,:]  (f32 1024x2048)
#define CI 1024
#define CO 2048
#define NB 256   // WY block size

typedef float  fx4  __attribute__((ext_vector_type(4)));
typedef short  s16x4 __attribute__((ext_vector_type(4)));
typedef short  s16x8 __attribute__((ext_vector_type(8)));
typedef unsigned short u16;

#define MFMA(a,b,c) __builtin_amdgcn_mfma_f32_16x16x32_bf16((a),(b),(c),0,0,0)

__device__ __forceinline__ u16 f2b(float x) {
    __hip_bfloat16 h = __float2bfloat16(x);
    return __builtin_bit_cast(u16, h);
}
__device__ __forceinline__ float b2f(u16 u) {
    __hip_bfloat16 h = __builtin_bit_cast(__hip_bfloat16, u);
    return __bfloat162float(h);
}

// ---------------- scalar utility kernels ----------------

__global__ __launch_bounds__(256) void colnorm2(const float* __restrict__ M, float* __restrict__ n2, int d) {
    int c = blockIdx.x * 256 + threadIdx.x;
    int r0 = blockIdx.y * 64;
    float s = 0.0f;
    for (int r = r0; r < r0 + 64; ++r) {
        float v = M[(size_t)r * d + c];
        s = fmaf(v, v, s);
    }
    atomicAdd(&n2[c], s);
}

__global__ __launch_bounds__(256) void init_W(float* __restrict__ W) {
    int c = blockIdx.x * 256 + threadIdx.x;
    int r = blockIdx.y;
    W[(size_t)r * CO + c] = (c == r) ? 1.0f : 0.0f;
}

__global__ __launch_bounds__(256) void reduce_S(const float* __restrict__ src, float* __restrict__ dst, int split) {
    int b = blockIdx.y;
    int i = blockIdx.x * 256 + threadIdx.x;
    const float* p = src + (size_t)b * split * NB * NB + i;
    float acc = 0.0f;
    for (int s = 0; s < split; ++s) acc += p[(size_t)s * NB * NB];
    dst[(size_t)b * NB * NB + i] = acc;
}

// ---------------- transpose + split-bf16 convert: T(a,b) = X(b,a) -> hi/lo planes ----------------
__global__ __launch_bounds__(256) void trans_planes(const float* __restrict__ X, int d,
                                                    u16* __restrict__ Th, u16* __restrict__ Tl) {
    size_t zo = (size_t)blockIdx.z * d * d;
    const float* Xz = X + zo;
    u16* Thz = Th + zo;
    u16* Tlz = Tl + zo;
    __shared__ float tile[32][33];
    int t = threadIdx.x;
    int r = t >> 3, c4 = (t & 7) * 4;
    int bx = blockIdx.x, by = blockIdx.y;
    fx4 v = *(const fx4*)(Xz + (size_t)(by * 32 + r) * d + bx * 32 + c4);
    tile[r][c4 + 0] = v[0]; tile[r][c4 + 1] = v[1]; tile[r][c4 + 2] = v[2]; tile[r][c4 + 3] = v[3];
    __syncthreads();
    int a = bx * 32 + r;
    u16 h[4], l[4];
    #pragma unroll
    for (int j = 0; j < 4; ++j) {
        float f = tile[c4 + j][r];
        u16 hb = f2b(f);
        h[j] = hb;
        l[j] = f2b(f - b2f(hb));
    }
    size_t o = (size_t)a * d + by * 32 + c4;
    *(s16x4*)&Thz[o] = *(s16x4*)&h[0];
    *(s16x4*)&Tlz[o] = *(s16x4*)&l[0];
}

// ---------------- blocked triangular inverse pipeline ----------------
// Ssc = D S D (in place over S)
__global__ __launch_bounds__(256) void scale_S(float* __restrict__ S,
                                               const float* __restrict__ n2u, const float* __restrict__ n2v) {
    int j = blockIdx.x, b = blockIdx.y, i = threadIdx.x;
    const float* n2 = (b < 4) ? (n2u + b * NB) : (n2v + (size_t)(b - 4) * NB);
    float inv = (1.0f / sqrtf(n2[j])) * (1.0f / sqrtf(n2[i]));
    S[(size_t)b * NB * NB + (size_t)j * NB + i] *= inv;
}

// Invert 64x64 diagonal blocks of R = 0.5I + triu(Ssc,1); one wave per (column, block, matrix).
// Output transposed: Tt[j_glob][i_glob] = T[i][j]; wave writes one contiguous 64-float row chunk.
__global__ __launch_bounds__(64) void diag_inv64(const float* __restrict__ Ssc, float* __restrict__ Tt) {
    int cg = blockIdx.x;            // 0..255: block d = cg>>6, col j = cg&63
    int b = blockIdx.y;             // matrix
    int d = cg >> 6, j = cg & 63;
    const float* S = Ssc + (size_t)b * NB * NB + (size_t)(d * 64) * NB + d * 64;  // ld NB
    float* Trow = Tt + (size_t)b * NB * NB + (size_t)(d * 64 + j) * NB + d * 64;
    int l = threadIdx.x;
    float x = (l == j) ? 2.0f : 0.0f;
    float a = 0.0f;
    int jpad = (j + 7) & ~7;
    float q0=0,q1=0,q2=0,q3=0,q4=0,q5=0,q6=0,q7=0;
#define LR(Q, R) { int _r = (R); if (_r >= 1 && _r <= j) Q = S[(size_t)_r * NB + l]; }
    LR(q0, jpad - 0) LR(q1, jpad - 1) LR(q2, jpad - 2) LR(q3, jpad - 3)
    LR(q4, jpad - 4) LR(q5, jpad - 5) LR(q6, jpad - 6) LR(q7, jpad - 7)
#define ST(Q) { \
    float yk = __shfl(x, k); \
    a = fmaf(Q, yk, a); \
    if (k <= j && l == k - 1) x = -2.0f * a; \
    int pr = k - 8; \
    if (pr >= 1) Q = S[(size_t)pr * NB + l]; \
    --k; }
    int k = jpad;
    int ng = jpad >> 3;
    for (int g = 0; g < ng; ++g) {
        ST(q0) ST(q1) ST(q2) ST(q3) ST(q4) ST(q5) ST(q6) ST(q7)
    }
#undef ST
#undef LR
    Trow[l] = x;
}

// Off-diagonal assembly (transposed domain): Ot = -Tt1 * G * Tt0, G = Ssc[r0-block rows, c0-block cols].
// mode 0: L1 tmp = G*Tt0 (s=64, z=24)    mode 1: L1 Ot = -Tt1*tmp (z=24)
// mode 2: L2 tmp = G*Tt0 (s=128, z=12)   mode 3: L2 Ot = -Tt1*tmp (z=12)
__global__ __launch_bounds__(128) void merge_gemm(const float* __restrict__ Ssc, float* __restrict__ Tt,
                                                  float* __restrict__ tmp, int mode) {
    int z = blockIdx.z;
    const float* A; const float* B; float* C;
    int lda, ldb, ldc, K; float sgn;
    if (mode == 0) {
        int b = z >> 1, p = z & 1; int c0 = p * 128, r0 = c0 + 64;
        A = Ssc + (size_t)b * NB * NB + (size_t)r0 * NB + c0; lda = NB;
        B = Tt  + (size_t)b * NB * NB + (size_t)c0 * NB + c0; ldb = NB;
        C = tmp + (size_t)z * 4096; ldc = 64; K = 64; sgn = 1.0f;
    } else if (mode == 1) {
        int b = z >> 1, p = z & 1; int c0 = p * 128, r0 = c0 + 64;
        A = Tt  + (size_t)b * NB * NB + (size_t)r0 * NB + r0; lda = NB;
        B = tmp + (size_t)z * 4096; ldb = 64;
        C = Tt  + (size_t)b * NB * NB + (size_t)r0 * NB + c0; ldc = NB; K = 64; sgn = -1.0f;
    } else if (mode == 2) {
        A = Ssc + (size_t)z * NB * NB + (size_t)128 * NB; lda = NB;
        B = Tt  + (size_t)z * NB * NB; ldb = NB;
        C = tmp + (size_t)z * 16384; ldc = 128; K = 128; sgn = 1.0f;
    } else {
        A = Tt  + (size_t)z * NB * NB + (size_t)128 * NB + 128; lda = NB;
        B = tmp + (size_t)z * 16384; ldb = 128;
        C = Tt  + (size_t)z * NB * NB + (size_t)128 * NB; ldc = NB; K = 128; sgn = -1.0f;
    }
    int m0 = blockIdx.y * 64, n0 = blockIdx.x * 64;
    __shared__ float As[16][64];
    __shared__ float Bs[16][64];
    int tid = threadIdx.x;
    int tm = (tid >> 4) * 8, tn = (tid & 15) * 4;
    int ar = tid >> 2, ac = (tid & 3) * 4;
    int bk = tid >> 4, bn = (tid & 15) * 4;
    float acc[8][4] = {};
    for (int k0 = 0; k0 < K; k0 += 16) {
        #pragma unroll
        for (int p = 0; p < 2; ++p) {
            int r = ar + p * 32;
            fx4 av = *(const fx4*)(A + (size_t)(m0 + r) * lda + k0 + ac);
            As[ac + 0][r] = av[0]; As[ac + 1][r] = av[1]; As[ac + 2][r] = av[2]; As[ac + 3][r] = av[3];
        }
        #pragma unroll
        for (int p = 0; p < 2; ++p) {
            int kk = bk + p * 8;
            *(fx4*)&Bs[kk][bn] = *(const fx4*)(B + (size_t)(k0 + kk) * ldb + n0 + bn);
        }
        __syncthreads();
        #pragma unroll
        for (int k = 0; k < 16; ++k) {
            fx4 alo = *(const fx4*)&As[k][tm];
            fx4 ahi = *(const fx4*)&As[k][tm + 4];
            fx4 bv  = *(const fx4*)&Bs[k][tn];
            float a[8] = {alo[0], alo[1], alo[2], alo[3], ahi[0], ahi[1], ahi[2], ahi[3]};
            float bb[4] = {bv[0], bv[1], bv[2], bv[3]};
            #pragma unroll
            for (int i = 0; i < 8; ++i)
                #pragma unroll
                for (int jj = 0; jj < 4; ++jj) acc[i][jj] = fmaf(a[i], bb[jj], acc[i][jj]);
        }
        __syncthreads();
    }
    #pragma unroll
    for (int i = 0; i < 8; ++i) {
        fx4 v = { sgn * acc[i][0], sgn * acc[i][1], sgn * acc[i][2], sgn * acc[i][3] };
        *(fx4*)(C + (size_t)(m0 + tm + i) * ldc + n0 + tn) = v;
    }
}

// Mt[j][i] = (i<=j) ? Tt[j][i]*invn_i*invn_j : 0
__global__ __launch_bounds__(256) void mt_scale(const float* __restrict__ Tt, float* __restrict__ Mt,
                                                const float* __restrict__ n2u, const float* __restrict__ n2v) {
    int j = blockIdx.x, b = blockIdx.y, i = threadIdx.x;
    const float* n2 = (b < 4) ? (n2u + b * NB) : (n2v + (size_t)(b - 4) * NB);
    float v = 0.0f;
    if (i <= j)
        v = Tt[(size_t)b * NB * NB + (size_t)j * NB + i] * (1.0f / sqrtf(n2[i])) * (1.0f / sqrtf(n2[j]));
    Mt[(size_t)b * NB * NB + (size_t)j * NB + i] = v;
}

// ---------------- MFMA common pieces ----------------
__device__ __forceinline__ void mma_step(const u16 Ah[][40], const u16 Al[][40],
                                         const u16 Bh[][40], const u16 Bl[][40],
                                         int wr, int wc, int lane, fx4 acc[2][2]) {
    int kb = (lane >> 4) * 8;
    int rl = lane & 15;
    s16x8 ah[2], al[2], bh[2], bl[2];
    #pragma unroll
    for (int f = 0; f < 2; ++f) {
        int ra = wr * 32 + f * 16 + rl;
        s16x4 p = *(const s16x4*)&Ah[ra][kb];
        s16x4 q = *(const s16x4*)&Ah[ra][kb + 4];
        ah[f] = __builtin_shufflevector(p, q, 0,1,2,3,4,5,6,7);
        p = *(const s16x4*)&Al[ra][kb];
        q = *(const s16x4*)&Al[ra][kb + 4];
        al[f] = __builtin_shufflevector(p, q, 0,1,2,3,4,5,6,7);
        int rb = wc * 32 + f * 16 + rl;
        p = *(const s16x4*)&Bh[rb][kb];
        q = *(const s16x4*)&Bh[rb][kb + 4];
        bh[f] = __builtin_shufflevector(p, q, 0,1,2,3,4,5,6,7);
        p = *(const s16x4*)&Bl[rb][kb];
        q = *(const s16x4*)&Bl[rb][kb + 4];
        bl[f] = __builtin_shufflevector(p, q, 0,1,2,3,4,5,6,7);
    }
    #pragma unroll
    for (int i = 0; i < 2; ++i)
        #pragma unroll
        for (int j = 0; j < 2; ++j) {
            acc[i][j] = MFMA(ah[i], bh[j], acc[i][j]);
            acc[i][j] = MFMA(ah[i], bl[j], acc[i][j]);
            acc[i][j] = MFMA(al[i], bh[j], acc[i][j]);
        }
}

template<int NPART>
__device__ __forceinline__ void stage_f32(const float* __restrict__ A, int ldA, size_t pstride,
                                          int m0, int k0, int t, u16 Dh[][40], u16 Dl[][40]) {
    int row = t >> 2, kc = (t & 3) * 8;
    const float* p = A + (size_t)(m0 + row) * ldA + k0 + kc;
    fx4 v0 = *(const fx4*)p;
    fx4 v1 = *(const fx4*)(p + 4);
    #pragma unroll
    for (int s = 1; s < NPART; ++s) {
        const float* q = p + (size_t)s * pstride;
        v0 += *(const fx4*)q;
        v1 += *(const fx4*)(q + 4);
    }
    u16 h[8], l[8];
    #pragma unroll
    for (int j = 0; j < 8; ++j) {
        float f = (j < 4) ? v0[j] : v1[j - 4];
        u16 hb = f2b(f);
        h[j] = hb;
        l[j] = f2b(f - b2f(hb));
    }
    *(s16x4*)&Dh[row][kc]     = *(s16x4*)&h[0];
    *(s16x4*)&Dh[row][kc + 4] = *(s16x4*)&h[4];
    *(s16x4*)&Dl[row][kc]     = *(s16x4*)&l[0];
    *(s16x4*)&Dl[row][kc + 4] = *(s16x4*)&l[4];
}

__device__ __forceinline__ void stage_planes(const u16* __restrict__ Ph, const u16* __restrict__ Pl, int ld,
                                             int n0, int k0, int t, u16 Dh[][40], u16 Dl[][40]) {
    int row = t >> 2, kc = (t & 3) * 8;
    size_t o = (size_t)(n0 + row) * ld + k0 + kc;
    s16x4 h0 = *(const s16x4*)(Ph + o);
    s16x4 h1 = *(const s16x4*)(Ph + o + 4);
    s16x4 l0 = *(const s16x4*)(Pl + o);
    s16x4 l1 = *(const s16x4*)(Pl + o + 4);
    *(s16x4*)&Dh[row][kc]     = h0;
    *(s16x4*)&Dh[row][kc + 4] = h1;
    *(s16x4*)&Dl[row][kc]     = l0;
    *(s16x4*)&Dl[row][kc + 4] = l1;
}

// ---------------- Gram partials via MFMA ----------------
__global__ __launch_bounds__(256) void gram_mfma(const u16* __restrict__ Xh, const u16* __restrict__ Xl,
                                                 int d, int split, int chunk, float* __restrict__ Sp) {
    int z = blockIdx.z;
    int zb = z / split, ks = z % split;
    int c0 = zb * NB, kb = ks * chunk;
    float* S = Sp + (size_t)z * NB * NB;
    __shared__ u16 Ah[64][40], Al[64][40], Bh[64][40], Bl[64][40];
    int t = threadIdx.x, lane = t & 63, w = t >> 6, wr = w >> 1, wc = w & 1;
    int i0 = blockIdx.y * 64, j0 = blockIdx.x * 64;
    fx4 acc[2][2] = {};
    for (int k0 = kb; k0 < kb + chunk; k0 += 32) {
        stage_planes(Xh, Xl, d, c0 + i0, k0, t, Ah, Al);
        stage_planes(Xh, Xl, d, c0 + j0, k0, t, Bh, Bl);
        __syncthreads();
        mma_step(Ah, Al, Bh, Bl, wr, wc, lane, acc);
        __syncthreads();
    }
    #pragma unroll
    for (int fr = 0; fr < 2; ++fr)
        #pragma unroll
        for (int fc = 0; fc < 2; ++fc) {
            int row = i0 + wr * 32 + fr * 16 + ((lane >> 4) << 2);
            int col = j0 + wc * 32 + fc * 16 + (lane & 15);
            #pragma unroll
            for (int r = 0; r < 4; ++r)
                S[(size_t)(row + r) * NB + col] = acc[fr][fc][r];
        }
}

// ---------------- TBt_z = RAW_blockz @ M_z^T, emitted as bf16 hi/lo planes ----------------
__global__ __launch_bounds__(256) void tbt_mfma(const float* __restrict__ RAW, int d,
                                                const u16* __restrict__ Mh, const u16* __restrict__ Ml,
                                                u16* __restrict__ TBh, u16* __restrict__ TBl) {
    int z = blockIdx.z;
    int c0 = z * NB;
    const u16* Mhz = Mh + (size_t)z * NB * NB;
    const u16* Mlz = Ml + (size_t)z * NB * NB;
    u16* Th = TBh + (size_t)z * d * NB;
    u16* Tl = TBl + (size_t)z * d * NB;
    __shared__ u16 Ah[64][40], Al[64][40], Bh[64][40], Bl[64][40];
    int t = threadIdx.x, lane = t & 63, w = t >> 6, wr = w >> 1, wc = w & 1;
    int m0 = blockIdx.y * 64, n0 = blockIdx.x * 64;
    fx4 acc[2][2] = {};
    for (int k0 = 0; k0 < NB; k0 += 32) {
        stage_f32<1>(RAW + c0, d, 0, m0, k0, t, Ah, Al);
        stage_planes(Mhz, Mlz, NB, n0, k0, t, Bh, Bl);
        __syncthreads();
        mma_step(Ah, Al, Bh, Bl, wr, wc, lane, acc);
        __syncthreads();
    }
    #pragma unroll
    for (int fr = 0; fr < 2; ++fr)
        #pragma unroll
        for (int fc = 0; fc < 2; ++fc) {
            int row = m0 + wr * 32 + fr * 16 + ((lane >> 4) << 2);
            int col = n0 + wc * 32 + fc * 16 + (lane & 15);
            #pragma unroll
            for (int r = 0; r < 4; ++r) {
                float f = acc[fr][fc][r];
                u16 hb = f2b(f);
                Th[(size_t)(row + r) * NB + col] = hb;
                Tl[(size_t)(row + r) * NB + col] = f2b(f - b2f(hb));
            }
        }
}

// ---------------- chain GEMM 1: P0parts[z] = W @ Bblk (B from transposed planes) ----------------
__global__ __launch_bounds__(256) void chain_part_mfma(const float* __restrict__ W,
                                                       const u16* __restrict__ Bth, const u16* __restrict__ Btl,
                                                       int ldB, float* __restrict__ Cparts, int kchunk) {
    int z = blockIdx.z;
    float* C = Cparts + (size_t)z * CI * NB;
    int kb = z * kchunk;
    __shared__ u16 Ah[64][40], Al[64][40], Bh[64][40], Bl[64][40];
    int t = threadIdx.x, lane = t & 63, w = t >> 6, wr = w >> 1, wc = w & 1;
    int m0 = blockIdx.y * 64, n0 = blockIdx.x * 64;
    fx4 acc[2][2] = {};
    for (int k0 = kb; k0 < kb + kchunk; k0 += 32) {
        stage_f32<1>(W, CO, 0, m0, k0, t, Ah, Al);
        stage_planes(Bth, Btl, ldB, n0, k0, t, Bh, Bl);
        __syncthreads();
        mma_step(Ah, Al, Bh, Bl, wr, wc, lane, acc);
        __syncthreads();
    }
    #pragma unroll
    for (int fr = 0; fr < 2; ++fr)
        #pragma unroll
        for (int fc = 0; fc < 2; ++fc) {
            int row = m0 + wr * 32 + fr * 16 + ((lane >> 4) << 2);
            int col = n0 + wc * 32 + fc * 16 + (lane & 15);
            #pragma unroll
            for (int r = 0; r < 4; ++r)
                C[(size_t)(row + r) * NB + col] = acc[fr][fc][r];
        }
}

// ---------------- reduce NPART fp32 partials -> bf16 hi/lo planes (once per chain step) ----------------
__global__ __launch_bounds__(256) void reduce_planes(const float* __restrict__ src, int npart,
                                                     u16* __restrict__ Ph, u16* __restrict__ Pl) {
    size_t idx = ((size_t)blockIdx.x * 256 + threadIdx.x) * 8;
    fx4 v0 = *(const fx4*)(src + idx);
    fx4 v1 = *(const fx4*)(src + idx + 4);
    for (int s = 1; s < npart; ++s) {
        const float* p = src + (size_t)s * CI * NB + idx;
        v0 += *(const fx4*)p;
        v1 += *(const fx4*)(p + 4);
    }
    u16 h[8], l[8];
    #pragma unroll
    for (int j = 0; j < 8; ++j) {
        float f = (j < 4) ? v0[j] : v1[j - 4];
        u16 hb = f2b(f);
        h[j] = hb;
        l[j] = f2b(f - b2f(hb));
    }
    *(s16x4*)&Ph[idx]     = *(s16x4*)&h[0];
    *(s16x4*)&Ph[idx + 4] = *(s16x4*)&h[4];
    *(s16x4*)&Pl[idx]     = *(s16x4*)&l[0];
    *(s16x4*)&Pl[idx + 4] = *(s16x4*)&l[4];
}

// ---------------- chain GEMM 2 (planes A): W -= P @ TB ----------------
__global__ __launch_bounds__(256) void chain_sub_pl(const u16* __restrict__ Ph, const u16* __restrict__ Pl,
                                                    const u16* __restrict__ TBh, const u16* __restrict__ TBl,
                                                    float* __restrict__ W) {
    __shared__ u16 Ah[64][40], Al[64][40], Bh[64][40], Bl[64][40];
    int t = threadIdx.x, lane = t & 63, w = t >> 6, wr = w >> 1, wc = w & 1;
    int m0 = blockIdx.y * 64, n0 = blockIdx.x * 64;
    fx4 acc[2][2] = {};
    for (int k0 = 0; k0 < NB; k0 += 32) {
        stage_planes(Ph, Pl, NB, m0, k0, t, Ah, Al);
        stage_planes(TBh, TBl, NB, n0, k0, t, Bh, Bl);
        __syncthreads();
        mma_step(Ah, Al, Bh, Bl, wr, wc, lane, acc);
        __syncthreads();
    }
    #pragma unroll
    for (int fr = 0; fr < 2; ++fr)
        #pragma unroll
        for (int fc = 0; fc < 2; ++fc) {
            int row = m0 + wr * 32 + fr * 16 + ((lane >> 4) << 2);
            int col = n0 + wc * 32 + fc * 16 + (lane & 15);
            #pragma unroll
            for (int r = 0; r < 4; ++r) {
                float* p = W + (size_t)(row + r) * CO + col;
                *p -= acc[fr][fc][r];
            }
        }
}

// ---------------- chain GEMM 2 (fp32 A, NPART=1): used for the ib=0 shortcut ----------------
template<int NPART>
__global__ __launch_bounds__(256) void chain_sub_mfma(const float* __restrict__ A, int ldA, size_t pstride,
                                                      const u16* __restrict__ TBh, const u16* __restrict__ TBl,
                                                      float* __restrict__ W) {
    __shared__ u16 Ah[64][40], Al[64][40], Bh[64][40], Bl[64][40];
    int t = threadIdx.x, lane = t & 63, w = t >> 6, wr = w >> 1, wc = w & 1;
    int m0 = blockIdx.y * 64, n0 = blockIdx.x * 64;
    fx4 acc[2][2] = {};
    for (int k0 = 0; k0 < NB; k0 += 32) {
        stage_f32<NPART>(A, ldA, pstride, m0, k0, t, Ah, Al);
        stage_planes(TBh, TBl, NB, n0, k0, t, Bh, Bl);
        __syncthreads();
        mma_step(Ah, Al, Bh, Bl, wr, wc, lane, acc);
        __syncthreads();
    }
    #pragma unroll
    for (int fr = 0; fr < 2; ++fr)
        #pragma unroll
        for (int fc = 0; fc < 2; ++fc) {
            int row = m0 + wr * 32 + fr * 16 + ((lane >> 4) << 2);
            int col = n0 + wc * 32 + fc * 16 + (lane & 15);
            #pragma unroll
            for (int r = 0; r < 4; ++r) {
                float* p = W + (size_t)(row + r) * CO + col;
                *p -= acc[fr][fc][r];
            }
        }
}

extern "C" void kernel_launch(void* const* d_in, const int* in_sizes, int n_in,
                              void* d_out, int out_size, void* d_ws, size_t ws_size,
                              hipStream_t stream) {
    const float* U = (const float*)d_in[0];   // 1024x1024
    const float* V = (const float*)d_in[1];   // 2048x2048
    float* W = (float*)d_out;                 // 1024x2048, evolving product

    char* ws = (char*)d_ws;
    float* P0p  = (float*)(ws);                           //  8 MB: split-K partials (tmp aliases early)
    float* tmp  = (float*)(ws);                           //  0.75 MB transient (merge levels, pre-chain)
    float* S    = (float*)(ws + ((size_t)8  << 20));      //  3 MB: S -> Ssc (in place) -> later Mt
    float* Tt   = (float*)(ws + ((size_t)11 << 20));      //  3 MB transposed scaled-domain T
    u16*   Mh   = (u16*)  (ws + ((size_t)14336 << 10));   //  1.5 MB
    u16*   Ml   = (u16*)  (ws + ((size_t)15872 << 10));   //  1.5 MB
    u16*   Ph   = (u16*)  (ws + ((size_t)17408 << 10));   //  0.5 MB P planes
    u16*   Pl   = (u16*)  (ws + ((size_t)17920 << 10));   //  0.5 MB
    u16*   TBh  = (u16*)  (ws + ((size_t)18 << 20));      // 10 MB
    u16*   TBl  = (u16*)  (ws + ((size_t)28 << 20));      // 10 MB
    u16*   Uth  = (u16*)  (ws + ((size_t)38 << 20));      //  2 MB
    u16*   Utl  = (u16*)  (ws + ((size_t)40 << 20));      //  2 MB
    u16*   Vth  = (u16*)  (ws + ((size_t)42 << 20));      //  8 MB
    u16*   Vtl  = (u16*)  (ws + ((size_t)50 << 20));      //  8 MB
    float* n2u  = (float*)(ws + ((size_t)58 << 20));      //  4 KB
    float* n2v  = n2u + CI;
    // Gram partials alias the TB region (consumed by reduce_S before TB is written)
    float* SpU  = (float*)(ws + ((size_t)18 << 20));      //  4 MB
    float* SpV  = (float*)(ws + ((size_t)22 << 20));      // 16 MB

    float* Su = S;  float* Sv = S + (size_t)4 * NB * NB;
    float* Mt = S;  // Mt reuses S region after Ssc consumed
    u16* TBhU = TBh;                       u16* TBlU = TBl;
    u16* TBhV = TBh + (size_t)4 * CI * NB; u16* TBlV = TBl + (size_t)4 * CI * NB;

    // 1) raw column norms
    hipMemsetAsync(n2u, 0, (CI + CO) * sizeof(float), stream);
    colnorm2<<<dim3(CI / 256, CI / 64), dim3(256), 0, stream>>>(U, n2u, CI);
    colnorm2<<<dim3(CO / 256, CO / 64), dim3(256), 0, stream>>>(V, n2v, CO);

    // 2) transpose+convert U,V to bf16 hi/lo planes
    trans_planes<<<dim3(CI / 32, CI / 32, 1), dim3(256), 0, stream>>>(U, CI, Uth, Utl);
    trans_planes<<<dim3(CO / 32, CO / 32, 1), dim3(256), 0, stream>>>(V, CO, Vth, Vtl);

    // 3) Gram partials via MFMA + reduce -> S
    gram_mfma<<<dim3(4, 4, 4 * 4), dim3(256), 0, stream>>>(Uth, Utl, CI, 4, CI / 4, SpU);
    gram_mfma<<<dim3(4, 4, 8 * 8), dim3(256), 0, stream>>>(Vth, Vtl, CO, 8, CO / 8, SpV);
    reduce_S<<<dim3(NB * NB / 256, 4), dim3(256), 0, stream>>>(SpU, Su, 4);
    reduce_S<<<dim3(NB * NB / 256, 8), dim3(256), 0, stream>>>(SpV, Sv, 8);

    // 4) blocked triangular inverse: Ssc (in place) -> diag -> 2 merge levels -> Mt
    scale_S<<<dim3(NB, 12), dim3(256), 0, stream>>>(S, n2u, n2v);
    hipMemsetAsync(Tt, 0, (size_t)12 * NB * NB * sizeof(float), stream);
    diag_inv64<<<dim3(NB, 12), dim3(64), 0, stream>>>(S, Tt);
    merge_gemm<<<dim3(1, 1, 24), dim3(128), 0, stream>>>(S, Tt, tmp, 0);
    merge_gemm<<<dim3(1, 1, 24), dim3(128), 0, stream>>>(S, Tt, tmp, 1);
    merge_gemm<<<dim3(2, 2, 12), dim3(128), 0, stream>>>(S, Tt, tmp, 2);
    merge_gemm<<<dim3(2, 2, 12), dim3(128), 0, stream>>>(S, Tt, tmp, 3);
    mt_scale<<<dim3(NB, 12), dim3(256), 0, stream>>>(Tt, Mt, n2u, n2v);   // Mt overwrites Ssc (dead)

    // 5) M planes + TBt planes
    trans_planes<<<dim3(NB / 32, NB / 32, 12), dim3(256), 0, stream>>>(Mt, NB, Mh, Ml);
    tbt_mfma<<<dim3(4, CI / 64, 4), dim3(256), 0, stream>>>(U, CI, Mh, Ml, TBhU, TBlU);
    tbt_mfma<<<dim3(4, CO / 64, 8), dim3(256), 0, stream>>>(V, CO, Mh + (size_t)4 * NB * NB,
                                                            Ml + (size_t)4 * NB * NB, TBhV, TBlV);

    // 6) W = [I | 0]
    init_W<<<dim3(CO / 256, CI), dim3(256), 0, stream>>>(W);

    // 7) U-phase
    chain_sub_mfma<1><<<dim3(CI / 64, CI / 64), dim3(256), 0, stream>>>(U, CI, 0, TBhU, TBlU, W);
    for (int ib = 1; ib < CI / NB; ++ib) {
        chain_part_mfma<<<dim3(4, CI / 64, 4), dim3(256), 0, stream>>>(
            W, Uth + (size_t)ib * NB * CI, Utl + (size_t)ib * NB * CI, CI, P0p, CI / 4);
        reduce_planes<<<dim3(CI * NB / 2048), dim3(256), 0, stream>>>(P0p, 4, Ph, Pl);
        chain_sub_pl<<<dim3(CI / 64, CI / 64), dim3(256), 0, stream>>>(
            Ph, Pl, TBhU + (size_t)ib * CI * NB, TBlU + (size_t)ib * CI * NB, W);
    }
    // 8) V-phase
    for (int ib = 0; ib < CO / NB; ++ib) {
        chain_part_mfma<<<dim3(4, CI / 64, 8), dim3(256), 0, stream>>>(
            W, Vth + (size_t)ib * NB * CO, Vtl + (size_t)ib * NB * CO, CO, P0p, CO / 8);
        reduce_planes<<<dim3(CI * NB / 2048), dim3(256), 0, stream>>>(P0p, 8, Ph, Pl);
        chain_sub_pl<<<dim3(CO / 64, CI / 64), dim3(256), 0, stream>>>(
            Ph, Pl, TBhV + (size_t)ib * CO * NB, TBlV + (size_t)ib * CO * NB, W);
    }
}